// Round 3
// baseline (6740.013 us; speedup 1.0000x reference)
//
#include <hip/hip_runtime.h>
#include <hip/hip_fp16.h>
#include <hip/hip_cooperative_groups.h>

namespace cg = cooperative_groups;

#define N_NODES 50000
#define N_EDGES 1600000
#define T_STEPS 50
#define DT      0.02f
#define NB      256    // buckets == cooperative blocks
#define NPB     196    // nodes per bucket (196*256 >= 50000)
#define CAP     6912   // max edges per bucket (mean 6272, sigma ~79)
#define TILE    4096   // edges per bucket_kernel block
#define G       8      // lanes per node group

// ---------------- setup: zero bucket cursors ----------------
__global__ __launch_bounds__(256) void zero_kernel(int* __restrict__ bucket_count) {
    bucket_count[threadIdx.x] = 0;
}

// ---------------- bucketing pass: staged, line-friendly appends ----------------
// record: low 16 = src, high 16 = fp16 weight; packed with tgt-within-bucket in u64
__global__ __launch_bounds__(256) void bucket_kernel(
    const int* __restrict__ src, const int* __restrict__ tgt,
    const float* __restrict__ sign, const float* __restrict__ syn_count,
    const float* __restrict__ syn_strength,
    int* __restrict__ bucket_count, unsigned long long* __restrict__ rec_buf)
{
    __shared__ int hist[NB], base_s[NB], cur[NB];
    int tid = threadIdx.x;
    hist[tid] = 0;
    __syncthreads();

    int e0 = blockIdx.x * TILE + tid;
    int bkt[16];
    unsigned long long item[16];
#pragma unroll
    for (int k = 0; k < 16; ++k) {
        int e = e0 + k * 256;
        if (e < N_EDGES) {
            int t = tgt[e];
            int b = t / NPB;
            int tl = t - b * NPB;
            float w = sign[e] * fmaxf(syn_count[e], 0.f) * fmaxf(syn_strength[e], 0.f);
            unsigned int rec = (unsigned int)src[e] |
                               ((unsigned int)__half_as_ushort(__float2half(w)) << 16);
            bkt[k] = b;
            item[k] = (unsigned long long)rec | ((unsigned long long)tl << 32);
            atomicAdd(&hist[b], 1);
        } else {
            bkt[k] = -1;
        }
    }
    __syncthreads();
    base_s[tid] = atomicAdd(&bucket_count[tid], hist[tid]);
    cur[tid] = 0;
    __syncthreads();
#pragma unroll
    for (int k = 0; k < 16; ++k) {
        if (bkt[k] >= 0) {
            int p = base_s[bkt[k]] + atomicAdd(&cur[bkt[k]], 1);
            if (p < CAP) rec_buf[(size_t)bkt[k] * CAP + p] = item[k];
        }
    }
}

// ---------------- persistent cooperative simulation ----------------
__global__ __launch_bounds__(1024) void sim_kernel(
    const float* __restrict__ bias, const float* __restrict__ time_const,
    const int* __restrict__ bucket_count,
    const unsigned long long* __restrict__ rec_buf,
    const float* __restrict__ x,
    float4* __restrict__ rates_a, float4* __restrict__ rates_b,
    float* __restrict__ out)
{
    __shared__ unsigned int lds_edges[CAP];   // 27.6 KB
    __shared__ int node_off[NPB + 1];
    __shared__ int s_cur[NPB];
    __shared__ float s_v[4][NPB];
    __shared__ float s_alpha[NPB];
    __shared__ float s_bias[NPB];

    cg::grid_group grid = cg::this_grid();
    int b   = blockIdx.x;
    int tid = threadIdx.x;
    int node_base = b * NPB;
    int n_nodes = min(NPB, N_NODES - node_base);

    // ---- phase A: load this bucket's edges, counting-sort by local target in LDS
    int cnt = min(bucket_count[b], CAP);
    unsigned long long it[7];
    int nit = 0;
    for (int i = tid; i < cnt; i += 1024) it[nit++] = rec_buf[(size_t)b * CAP + i];

    if (tid < NPB) s_cur[tid] = 0;
    __syncthreads();
    for (int j = 0; j < nit; ++j) atomicAdd(&s_cur[(int)(it[j] >> 32)], 1);
    __syncthreads();
    if (tid == 0) {
        int r = 0;
        for (int n = 0; n < n_nodes; ++n) { node_off[n] = r; r += s_cur[n]; }
        node_off[n_nodes] = r;
    }
    __syncthreads();
    if (tid < n_nodes) s_cur[tid] = node_off[tid];
    __syncthreads();
    for (int j = 0; j < nit; ++j) {
        int tl = (int)(it[j] >> 32);
        int p = atomicAdd(&s_cur[tl], 1);
        lds_edges[p] = (unsigned int)it[j];
    }

    // ---- phase B: per-node persistent state
    if (tid < n_nodes) {
        int gn = node_base + tid;
        float bb  = bias[gn];
        float tau = fmaxf(time_const[gn], DT);
        s_alpha[tid] = DT / tau;
        s_bias[tid]  = bb;
        s_v[0][tid] = bb; s_v[1][tid] = bb; s_v[2][tid] = bb; s_v[3][tid] = bb;
        float r = fmaxf(bb, 0.f);
        rates_a[gn] = make_float4(r, r, r, r);
    }
    __threadfence();
    grid.sync();

    const int TN = T_STEPS * N_NODES;
    int group = tid >> 3;          // 128 groups of G=8
    int lane  = tid & (G - 1);

    for (int t = 0; t < T_STEPS; ++t) {
        const float4* __restrict__ rin  = (t & 1) ? rates_b : rates_a;
        float4*       __restrict__ rout = (t & 1) ? rates_a : rates_b;

        for (int n = group; n < n_nodes; n += 128) {
            int beg = node_off[n], end = node_off[n + 1];
            float4 acc = make_float4(0.f, 0.f, 0.f, 0.f);
            for (int i = beg + lane; i < end; i += G) {
                unsigned int rec = lds_edges[i];
                float w = __half2float(__ushort_as_half((unsigned short)(rec >> 16)));
                float4 r = rin[rec & 0xFFFFu];
                acc.x = fmaf(r.x, w, acc.x);
                acc.y = fmaf(r.y, w, acc.y);
                acc.z = fmaf(r.z, w, acc.z);
                acc.w = fmaf(r.w, w, acc.w);
            }
#pragma unroll
            for (int msk = 1; msk < G; msk <<= 1) {
                acc.x += __shfl_xor(acc.x, msk, 64);
                acc.y += __shfl_xor(acc.y, msk, 64);
                acc.z += __shfl_xor(acc.z, msk, 64);
                acc.w += __shfl_xor(acc.w, msk, 64);
            }
            if (lane < 4) {        // lane l handles batch element l
                float sum = (lane == 0) ? acc.x : (lane == 1) ? acc.y
                          : (lane == 2) ? acc.z : acc.w;
                float a  = s_alpha[n];
                float bb = s_bias[n];
                int gn = node_base + n;
                int oi = lane * TN + t * N_NODES + gn;
                float vv = s_v[lane][n];
                float vn = vv + a * (bb + sum + x[oi] - vv);
                s_v[lane][n] = vn;
                float r = fmaxf(vn, 0.f);
                ((float*)&rout[gn])[lane] = r;
                out[oi] = r;
            }
        }
        __threadfence();
        grid.sync();
    }
}

// ---------------- launch ----------------
extern "C" void kernel_launch(void* const* d_in, const int* in_sizes, int n_in,
                              void* d_out, int out_size, void* d_ws, size_t ws_size,
                              hipStream_t stream) {
    const float* x            = (const float*)d_in[0];
    const float* bias         = (const float*)d_in[1];
    const float* time_const   = (const float*)d_in[2];
    const float* sign         = (const float*)d_in[3];
    const float* syn_count    = (const float*)d_in[4];
    const float* syn_strength = (const float*)d_in[5];
    const int*   src_idx      = (const int*)d_in[6];
    const int*   tgt_idx      = (const int*)d_in[7];
    float* out = (float*)d_out;

    char* ws = (char*)d_ws;
    size_t off = 0;
    auto alloc = [&](size_t bytes) -> void* {
        void* p = ws + off;
        off = (off + bytes + 255) & ~(size_t)255;
        return p;
    };
    float4* rates_a = (float4*)alloc((size_t)N_NODES * 16);
    float4* rates_b = (float4*)alloc((size_t)N_NODES * 16);
    int* bucket_count = (int*)alloc((size_t)NB * 4);
    unsigned long long* rec_buf =
        (unsigned long long*)alloc((size_t)NB * CAP * 8);   // 14.2 MB

    zero_kernel<<<1, 256, 0, stream>>>(bucket_count);
    int nb_tiles = (N_EDGES + TILE - 1) / TILE;
    bucket_kernel<<<nb_tiles, 256, 0, stream>>>(src_idx, tgt_idx, sign, syn_count,
                                                syn_strength, bucket_count, rec_buf);

    void* args[] = { (void*)&bias, (void*)&time_const, (void*)&bucket_count,
                     (void*)&rec_buf, (void*)&x, (void*)&rates_a, (void*)&rates_b,
                     (void*)&out };
    hipLaunchCooperativeKernel((const void*)sim_kernel, dim3(NB), dim3(1024),
                               args, 0, stream);
}

// Round 5
// 735.835 us; speedup vs baseline: 9.1597x; 9.1597x over previous
//
#include <hip/hip_runtime.h>
#include <hip/hip_fp16.h>

#define N_NODES 50000
#define N_EDGES 1600000
#define T_STEPS 50
#define DT      0.02f
#define NB      256    // buckets
#define NPB     196    // nodes per bucket (196*256 >= 50000)
#define CAP     6912   // max edges per bucket (mean 6272, +8 sigma)
#define TILE    4096   // edges per bucket_kernel block
#define G       8      // lanes per node group in step kernel

// ---------------- setup ----------------

__global__ __launch_bounds__(256) void zero_kernel(int* __restrict__ bucket_count) {
    bucket_count[threadIdx.x] = 0;
}

__global__ __launch_bounds__(256) void init_kernel(
    const float* __restrict__ bias, const float* __restrict__ time_const,
    float* __restrict__ alpha, float* __restrict__ v /* [4][N] SoA */,
    float4* __restrict__ rates0)
{
    int n = blockIdx.x * 256 + threadIdx.x;
    if (n >= N_NODES) return;
    float tau = fmaxf(time_const[n], DT);
    alpha[n] = DT / tau;
    float b = bias[n];
    v[n] = b; v[N_NODES + n] = b; v[2 * N_NODES + n] = b; v[3 * N_NODES + n] = b;
    float r = fmaxf(b, 0.0f);
    rates0[n] = make_float4(r, r, r, r);
}

// ---------------- bucketing: staged, line-friendly appends ----------------
// u64 item: low 32 = record (src | fp16w<<16), high 32 = target-within-bucket
__global__ __launch_bounds__(256) void bucket_kernel(
    const int* __restrict__ src, const int* __restrict__ tgt,
    const float* __restrict__ sign, const float* __restrict__ syn_count,
    const float* __restrict__ syn_strength,
    int* __restrict__ bucket_count, unsigned long long* __restrict__ rec_buf)
{
    __shared__ int hist[NB], base_s[NB], cur[NB];
    int tid = threadIdx.x;
    hist[tid] = 0;
    __syncthreads();

    int e0 = blockIdx.x * TILE + tid;
    int bkt[16];
    unsigned long long item[16];
#pragma unroll
    for (int k = 0; k < 16; ++k) {
        int e = e0 + k * 256;
        if (e < N_EDGES) {
            int t = tgt[e];
            int b = t / NPB;
            int tl = t - b * NPB;
            float w = sign[e] * fmaxf(syn_count[e], 0.f) * fmaxf(syn_strength[e], 0.f);
            unsigned int rec = (unsigned int)src[e] |
                               ((unsigned int)__half_as_ushort(__float2half(w)) << 16);
            bkt[k] = b;
            item[k] = (unsigned long long)rec | ((unsigned long long)tl << 32);
            atomicAdd(&hist[b], 1);
        } else {
            bkt[k] = -1;
        }
    }
    __syncthreads();
    base_s[tid] = atomicAdd(&bucket_count[tid], hist[tid]);
    cur[tid] = 0;
    __syncthreads();
#pragma unroll
    for (int k = 0; k < 16; ++k) {
        if (bkt[k] >= 0) {
            int p = base_s[bkt[k]] + atomicAdd(&cur[bkt[k]], 1);
            if (p < CAP) rec_buf[(size_t)bkt[k] * CAP + p] = item[k];
        }
    }
}

// ---------------- per-bucket counting sort -> global CSR ----------------
__global__ __launch_bounds__(256) void sort_kernel(
    const int* __restrict__ bucket_count,
    const unsigned long long* __restrict__ rec_buf,
    unsigned int* __restrict__ edges_g, int* __restrict__ offsets)
{
    __shared__ unsigned int sorted[CAP];          // 27.6 KB
    __shared__ int cnts[NB];
    __shared__ int loc_off[NPB + 1];
    __shared__ int loc_cur[NPB];

    int b = blockIdx.x;
    int tid = threadIdx.x;
    int node_base = b * NPB;
    int n_nodes = min(NPB, N_NODES - node_base);

    cnts[tid] = min(bucket_count[tid], CAP);
    if (tid < NPB) loc_cur[tid] = 0;
    __syncthreads();

    // exclusive prefix over 256 bucket counts (serial, cheap)
    __shared__ int ebase_s;
    if (tid == 0) {
        int r = 0;
        for (int i = 0; i < b; ++i) r += cnts[i];
        ebase_s = r;
    }
    __syncthreads();
    int ebase = ebase_s;
    int cnt = cnts[b];

    // pass 1: histogram by local target
    for (int i = tid; i < cnt; i += 256) {
        unsigned long long it = rec_buf[(size_t)b * CAP + i];
        atomicAdd(&loc_cur[(int)(it >> 32)], 1);
    }
    __syncthreads();
    if (tid == 0) {
        int r = 0;
        for (int n = 0; n < n_nodes; ++n) { loc_off[n] = r; r += loc_cur[n]; }
        loc_off[n_nodes] = r;
    }
    __syncthreads();
    if (tid < n_nodes) loc_cur[tid] = loc_off[tid];
    __syncthreads();

    // pass 2: place (rec_buf re-read is L2-hot)
    for (int i = tid; i < cnt; i += 256) {
        unsigned long long it = rec_buf[(size_t)b * CAP + i];
        int p = atomicAdd(&loc_cur[(int)(it >> 32)], 1);
        sorted[p] = (unsigned int)it;
    }
    __syncthreads();

    // coalesced CSR write + offsets
    for (int i = tid; i < cnt; i += 256) edges_g[ebase + i] = sorted[i];
    for (int n = tid; n < n_nodes; n += 256) offsets[node_base + n] = ebase + loc_off[n];
    if (b == NB - 1 && tid == 0) offsets[N_NODES] = ebase + cnt;
}

// ---------------- per-step fused gather + Euler update ----------------
__device__ __forceinline__ float rec_w(unsigned int rec) {
    return __half2float(__ushort_as_half((unsigned short)(rec >> 16)));
}

__global__ __launch_bounds__(256) void step_kernel(
    const float4* __restrict__ rates_in, float* __restrict__ rates_out,
    float* __restrict__ v /* [4][N] SoA */,
    const float* __restrict__ alpha, const float* __restrict__ bias,
    const int* __restrict__ offsets, const unsigned int* __restrict__ edges,
    const float* __restrict__ x, float* __restrict__ out, int t, int nblk)
{
    // XCD-contiguous swizzle (BIJECTIVE): first nb8*8 blocks are swizzled so
    // each XCD's blocks cover a contiguous node range; tail maps identity.
    int nb8 = nblk / 8;
    int idx = blockIdx.x;
    int node_block = (idx < nb8 * 8) ? (idx % 8) * nb8 + idx / 8 : idx;
    int node = node_block * (256 / G) + ((int)threadIdx.x / G);
    int lane = threadIdx.x & (G - 1);
    if (node >= N_NODES) return;

    int beg = offsets[node], end = offsets[node + 1];
    float4 acc = make_float4(0.f, 0.f, 0.f, 0.f);

    // unroll-4 software pipeline; pad records (0) are w=0 no-ops
    int i = beg + lane;
    unsigned int r0 = (i          < end) ? edges[i]         : 0u;
    unsigned int r1 = (i + G      < end) ? edges[i + G]     : 0u;
    unsigned int r2 = (i + 2 * G  < end) ? edges[i + 2 * G] : 0u;
    unsigned int r3 = (i + 3 * G  < end) ? edges[i + 3 * G] : 0u;
    while (i < end) {
        unsigned int n0 = (i + 4 * G < end) ? edges[i + 4 * G] : 0u;
        unsigned int n1 = (i + 5 * G < end) ? edges[i + 5 * G] : 0u;
        unsigned int n2 = (i + 6 * G < end) ? edges[i + 6 * G] : 0u;
        unsigned int n3 = (i + 7 * G < end) ? edges[i + 7 * G] : 0u;
        float4 a0 = rates_in[r0 & 0xFFFFu];
        float4 a1 = rates_in[r1 & 0xFFFFu];
        float4 a2 = rates_in[r2 & 0xFFFFu];
        float4 a3 = rates_in[r3 & 0xFFFFu];
        float w0 = rec_w(r0), w1 = rec_w(r1), w2 = rec_w(r2), w3 = rec_w(r3);
        acc.x = fmaf(a0.x, w0, acc.x); acc.y = fmaf(a0.y, w0, acc.y);
        acc.z = fmaf(a0.z, w0, acc.z); acc.w = fmaf(a0.w, w0, acc.w);
        acc.x = fmaf(a1.x, w1, acc.x); acc.y = fmaf(a1.y, w1, acc.y);
        acc.z = fmaf(a1.z, w1, acc.z); acc.w = fmaf(a1.w, w1, acc.w);
        acc.x = fmaf(a2.x, w2, acc.x); acc.y = fmaf(a2.y, w2, acc.y);
        acc.z = fmaf(a2.z, w2, acc.z); acc.w = fmaf(a2.w, w2, acc.w);
        acc.x = fmaf(a3.x, w3, acc.x); acc.y = fmaf(a3.y, w3, acc.y);
        acc.z = fmaf(a3.z, w3, acc.z); acc.w = fmaf(a3.w, w3, acc.w);
        r0 = n0; r1 = n1; r2 = n2; r3 = n3;
        i += 4 * G;
    }

#pragma unroll
    for (int m = 1; m < G; m <<= 1) {
        acc.x += __shfl_xor(acc.x, m, 64);
        acc.y += __shfl_xor(acc.y, m, 64);
        acc.z += __shfl_xor(acc.z, m, 64);
        acc.w += __shfl_xor(acc.w, m, 64);
    }

    if (lane < 4) {   // lane l handles batch element l
        float sum = (lane == 0) ? acc.x : (lane == 1) ? acc.y
                  : (lane == 2) ? acc.z : acc.w;
        float a = alpha[node];
        float b = bias[node];
        const int TN = T_STEPS * N_NODES;
        int vi = lane * N_NODES + node;
        int oi = lane * TN + t * N_NODES + node;
        float vv = v[vi];
        float vn = vv + a * (b + sum + x[oi] - vv);
        v[vi] = vn;
        float r = fmaxf(vn, 0.f);
        rates_out[node * 4 + lane] = r;
        out[oi] = r;
    }
}

// ---------------- launch ----------------

extern "C" void kernel_launch(void* const* d_in, const int* in_sizes, int n_in,
                              void* d_out, int out_size, void* d_ws, size_t ws_size,
                              hipStream_t stream) {
    const float* x            = (const float*)d_in[0];
    const float* bias         = (const float*)d_in[1];
    const float* time_const   = (const float*)d_in[2];
    const float* sign         = (const float*)d_in[3];
    const float* syn_count    = (const float*)d_in[4];
    const float* syn_strength = (const float*)d_in[5];
    const int*   src_idx      = (const int*)d_in[6];
    const int*   tgt_idx      = (const int*)d_in[7];
    float* out = (float*)d_out;

    char* ws = (char*)d_ws;
    size_t off = 0;
    auto alloc = [&](size_t bytes) -> void* {
        void* p = ws + off;
        off = (off + bytes + 255) & ~(size_t)255;
        return p;
    };
    float* v        = (float*)alloc((size_t)N_NODES * 4 * 4);   // [4][N] SoA
    float* rates_a  = (float*)alloc((size_t)N_NODES * 16);
    float* rates_b  = (float*)alloc((size_t)N_NODES * 16);
    float* alpha    = (float*)alloc((size_t)N_NODES * 4);
    int*   offsets  = (int*)  alloc((size_t)(N_NODES + 1) * 4);
    int*   bucket_count = (int*)alloc((size_t)NB * 4);
    unsigned int* edges = (unsigned int*)alloc((size_t)N_EDGES * 4);
    unsigned long long* rec_buf =
        (unsigned long long*)alloc((size_t)NB * CAP * 8);   // 14.2 MB

    int nb_nodes = (N_NODES + 255) / 256;
    int nb_tiles = (N_EDGES + TILE - 1) / TILE;

    zero_kernel<<<1, 256, 0, stream>>>(bucket_count);
    init_kernel<<<nb_nodes, 256, 0, stream>>>(bias, time_const, alpha, v,
                                              (float4*)rates_a);
    bucket_kernel<<<nb_tiles, 256, 0, stream>>>(src_idx, tgt_idx, sign, syn_count,
                                                syn_strength, bucket_count, rec_buf);
    sort_kernel<<<NB, 256, 0, stream>>>(bucket_count, rec_buf, edges, offsets);

    int nblk = (N_NODES + (256 / G) - 1) / (256 / G);
    for (int t = 0; t < T_STEPS; ++t) {
        const float4* rin  = (const float4*)((t & 1) ? rates_b : rates_a);
        float*        rout = (t & 1) ? rates_a : rates_b;
        step_kernel<<<nblk, 256, 0, stream>>>(rin, rout, v, alpha, bias,
                                              offsets, edges, x, out, t, nblk);
    }
}